// Round 3
// baseline (117.082 us; speedup 1.0000x reference)
//
#include <hip/hip_runtime.h>

// Problem constants (fixed by setup_inputs)
#define NB   16
#define NH   512
#define NW   512
#define RAD  4            // window 9 -> radius 4
#define PADW (NW + 2*RAD) // 520, +4 zero pad each side for horizontal window
#define BH   8            // output rows per band
#define TX   128          // threads across x (each owns 4 cols)
#define BANDS 2           // bands per workgroup
#define NTHREADS 256
#define STRIPES (NH / (BH * BANDS)) // 32
#define NBLOCKS (NB * STRIPES)      // 512
#define EPSF 1e-5f

__device__ __forceinline__ float lncc_val(float Sa, float Sb, float Saa, float Sbb, float Sab) {
    const float inv_n = 1.0f / 81.0f;
    float ma  = Sa * inv_n;
    float mb  = Sb * inv_n;
    // faithful to reference: raw local sum of squares minus mean^2, clipped at 0
    float va  = fmaxf(Saa - ma * ma, 0.0f);
    float vb  = fmaxf(Sbb - mb * mb, 0.0f);
    float cov = Sab - ma * mb;
    return cov * rsqrtf((va + EPSF) * (vb + EPSF));
}

__global__ __launch_bounds__(NTHREADS, 2)
void lncc_main(const float* __restrict__ pred,
               const float* __restrict__ targ,
               const float* __restrict__ mask,
               float* __restrict__ part)
{
    __shared__ float LV[BANDS][10][PADW];
    __shared__ float wred[8];

    const int tid  = threadIdx.x;
    const int tx   = tid & (TX - 1);
    const int ty   = tid >> 7;
    const int col0 = tx * 4;

    const int b  = blockIdx.x / STRIPES;
    const int s  = blockIdx.x % STRIPES;
    const int y0 = (s * BANDS + ty) * BH;

    // zero LDS once (only the 4-wide pads actually need to stay zero)
    {
        float* lf = &LV[0][0][0];
        for (int i = tid; i < BANDS * 10 * PADW; i += NTHREADS) lf[i] = 0.0f;
    }
    __syncthreads();

    const size_t hw   = (size_t)NH * NW;
    const float* prow = pred + (size_t)b * hw;
    const float* trow = targ + (size_t)b * hw;
    const float* mrow = mask + (size_t)b * 2 * hw;

    // running vertical sums: 10 quantities x 4 cols
    float V[10][4];
    #pragma unroll
    for (int q = 0; q < 10; ++q) {
        #pragma unroll
        for (int c = 0; c < 4; ++c) V[q][c] = 0.0f;
    }

    // add (sgn=+1) or subtract (sgn=-1) one input row's products into V
    auto accum = [&](int y, float sgn) {
        size_t off = (size_t)y * NW + col0;
        float4 pv = *reinterpret_cast<const float4*>(prow + off);
        float4 tv = *reinterpret_cast<const float4*>(trow + off);
        float4 m0 = *reinterpret_cast<const float4*>(mrow + off);
        float4 m1 = *reinterpret_cast<const float4*>(mrow + off + hw);
        float pa[4] = {pv.x, pv.y, pv.z, pv.w};
        float ta[4] = {tv.x, tv.y, tv.z, tv.w};
        float c0[4] = {m0.x, m0.y, m0.z, m0.w};
        float c1[4] = {m1.x, m1.y, m1.z, m1.w};
        #pragma unroll
        for (int c = 0; c < 4; ++c) {
            float p  = pa[c], t = ta[c];
            // argmax over 2 channels: 1 iff mask[1] > mask[0] (ties -> 0)
            float mm = (c1[c] > c0[c]) ? sgn : 0.0f;
            float pp = p * p, tt = t * t, pt = p * t;
            V[0][c] += sgn * p;  V[1][c] += sgn * t;
            V[2][c] += sgn * pp; V[3][c] += sgn * tt; V[4][c] += sgn * pt;
            V[5][c] += mm * p;   V[6][c] += mm * t;
            V[7][c] += mm * pp;  V[8][c] += mm * tt;  V[9][c] += mm * pt;
        }
    };

    // warm-up: rows [y0-4, y0+3] (zero-padded outside image)
    #pragma unroll
    for (int j = -RAD; j < RAD; ++j) {
        int y = y0 + j;
        if (y >= 0 && y < NH) accum(y, 1.0f);
    }

    float sum_p = 0.0f, sum_n = 0.0f;

    for (int r = 0; r < BH; ++r) {
        int y  = y0 + r;
        int ye = y + RAD;
        if (ye < NH) accum(ye, 1.0f);   // V now spans rows [y-4, y+4]

        // stage vertical sums for this row
        #pragma unroll
        for (int q = 0; q < 10; ++q) {
            float4 v = make_float4(V[q][0], V[q][1], V[q][2], V[q][3]);
            *reinterpret_cast<float4*>(&LV[ty][q][RAD + col0]) = v;
        }
        __syncthreads();

        // horizontal 9-tap box via 12-wide window + register sliding
        float Hh[10][4];
        #pragma unroll
        for (int q = 0; q < 10; ++q) {
            float4 a  = *reinterpret_cast<const float4*>(&LV[ty][q][col0]);
            float4 bq = *reinterpret_cast<const float4*>(&LV[ty][q][col0 + 4]);
            float4 cq = *reinterpret_cast<const float4*>(&LV[ty][q][col0 + 8]);
            float w0=a.x,  w1=a.y,  w2=a.z,  w3=a.w;
            float w4=bq.x, w5=bq.y, w6=bq.z, w7=bq.w;
            float w8=cq.x, w9=cq.y, w10=cq.z, w11=cq.w;
            float h = ((w0+w1)+(w2+w3)) + ((w4+w5)+(w6+w7)) + w8;
            Hh[q][0] = h;
            h += w9  - w0; Hh[q][1] = h;
            h += w10 - w1; Hh[q][2] = h;
            h += w11 - w2; Hh[q][3] = h;
        }
        __syncthreads();  // protect LDS before next row's writes

        #pragma unroll
        for (int c = 0; c < 4; ++c) {
            float Sa=Hh[0][c], Sb=Hh[1][c], Saa=Hh[2][c], Sbb=Hh[3][c], Sab=Hh[4][c];
            float Ma=Hh[5][c], Mb=Hh[6][c], Maa=Hh[7][c], Mbb=Hh[8][c], Mab=Hh[9][c];
            sum_n += lncc_val(Ma, Mb, Maa, Mbb, Mab);
            sum_p += lncc_val(Sa - Ma, Sb - Mb, Saa - Maa, Sbb - Mbb, Sab - Mab);
        }

        // slide: subtract leaving row (re-load; hits cache, inputs fit in L3)
        if (r < BH - 1) {
            int yl = y - RAD;
            if (yl >= 0) accum(yl, -1.0f);
        }
    }

    // block reduction -> per-block partials (deterministic, no atomics)
    #pragma unroll
    for (int off = 32; off > 0; off >>= 1) {
        sum_p += __shfl_down(sum_p, off, 64);
        sum_n += __shfl_down(sum_n, off, 64);
    }
    int wave = tid >> 6, lane = tid & 63;
    if (lane == 0) { wred[wave] = sum_p; wred[4 + wave] = sum_n; }
    __syncthreads();
    if (tid == 0) {
        float sp = wred[0] + wred[1] + wred[2] + wred[3];
        float sn = wred[4] + wred[5] + wred[6] + wred[7];
        part[blockIdx.x]           = sp;
        part[NBLOCKS + blockIdx.x] = sn;
    }
}

__global__ void lncc_finalize(const float* __restrict__ part, float* __restrict__ out) {
    __shared__ float w[8];
    int tid = threadIdx.x; // 256 threads
    float sp = 0.0f, sn = 0.0f;
    for (int i = tid; i < NBLOCKS; i += 256) {
        sp += part[i];
        sn += part[NBLOCKS + i];
    }
    #pragma unroll
    for (int off = 32; off > 0; off >>= 1) {
        sp += __shfl_down(sp, off, 64);
        sn += __shfl_down(sn, off, 64);
    }
    int wave = tid >> 6, lane = tid & 63;
    if (lane == 0) { w[wave] = sp; w[4 + wave] = sn; }
    __syncthreads();
    if (tid == 0) {
        double SP = (double)w[0] + (double)w[1] + (double)w[2] + (double)w[3];
        double SN = (double)w[4] + (double)w[5] + (double)w[6] + (double)w[7];
        const double npix = (double)NB * (double)NH * (double)NW;
        double mp = SP / npix;
        double mn = SN / npix;
        // LOSS_WEIGHT * (BALANCE*(1-mp) - (1-BALANCE)*(1-mn))
        out[0] = (float)(0.2 * (1.0 - mp) - 0.8 * (1.0 - mn));
    }
}

extern "C" void kernel_launch(void* const* d_in, const int* in_sizes, int n_in,
                              void* d_out, int out_size, void* d_ws, size_t ws_size,
                              hipStream_t stream) {
    const float* pred = (const float*)d_in[0];
    const float* targ = (const float*)d_in[1];
    const float* mask = (const float*)d_in[2];
    float* part = (float*)d_ws;  // 2*NBLOCKS floats, every slot written each launch

    lncc_main<<<dim3(NBLOCKS), dim3(NTHREADS), 0, stream>>>(pred, targ, mask, part);
    lncc_finalize<<<dim3(1), dim3(256), 0, stream>>>(part, (float*)d_out);
}